// Round 1
// baseline (2071.378 us; speedup 1.0000x reference)
//
#include <hip/hip_runtime.h>

// Problem constants
#define TSEG 8
#define NBC 4          // clips
#define NBT 32         // B*T
#define CIN 256
#define CH 64
#define HIN 112
#define WIN_ 112
#define HO 56
#define WO 56
// padded yn dims
#define TPD 12
#define HPD 64
#define WPD 64
#define NBSTR 644      // padded LDS plane stride (floats) for corr staging

#define YNP_ELEMS ((size_t)NBC * TPD * HPD * WPD * CH)   // 12,582,912 floats

// ---------------------------------------------------------------------------
// Kernel 1: conv3x3 s2 p1 + BN(eval) + ReLU + per-pixel L2 norm over channels,
// writing into zero-padded yn buffer [b][t+2][h+4][w+4][c].
// Block: 256 threads = 16 cout-groups(x4 couts) x 16 pixel-groups(x7 pixels).
// Tile: one bt, 2 output rows (112 pixels), all 64 couts.
// ---------------------------------------------------------------------------
__global__ __launch_bounds__(256) void conv_norm_k(
    const float* __restrict__ x, const float* __restrict__ wgt,
    const float* __restrict__ gamma, const float* __restrict__ beta,
    const float* __restrict__ mean, const float* __restrict__ var,
    float* __restrict__ ynp)
{
    __shared__ float in_t[16 * 5 * 114];   // [ci][ir(5)][iw(114)] : 9120 floats
    __shared__ float w_t[16 * 9 * 64];     // [ci][k(9)][cout(64)] : 9216 floats

    const int tid = threadIdx.x;
    const int h0  = blockIdx.x * 2;        // first output row of tile
    const int bt  = blockIdx.y;
    const int coutg = tid & 15;
    const int c4    = coutg * 4;
    const int pixg  = tid >> 4;

    int rowoff[7], prow[7], pcol[7];
#pragma unroll
    for (int i = 0; i < 7; ++i) {
        int p = pixg * 7 + i;              // 0..111
        int rr = p / 56, cc = p - rr * 56;
        prow[i] = rr; pcol[i] = cc;
        rowoff[i] = (2 * rr) * 114 + 2 * cc;
    }

    float acc[7][4];
#pragma unroll
    for (int i = 0; i < 7; ++i) { acc[i][0]=0.f; acc[i][1]=0.f; acc[i][2]=0.f; acc[i][3]=0.f; }

    const float* xb = x + (size_t)bt * CIN * HIN * WIN_;

    for (int cb = 0; cb < 16; ++cb) {
        __syncthreads();
        // stage input rows 2*h0-1 .. 2*h0+3, cols -1..112, 16 channels
        for (int e = tid; e < 9120; e += 256) {
            int ci  = e / 570;
            int rem = e - ci * 570;
            int ir  = rem / 114;
            int iw  = rem - ir * 114 - 1;
            int ih  = 2 * h0 - 1 + ir;
            float v = 0.f;
            if (ih >= 0 && ih < HIN && iw >= 0 && iw < WIN_)
                v = xb[((size_t)(cb * 16 + ci) * HIN + ih) * WIN_ + iw];
            in_t[e] = v;
        }
        // stage weights: w_t[ci][k][cout] = wgt[cout][cb*16+ci][k]
        for (int e = tid; e < 9216; e += 256) {
            int cout = e & 63;
            int rem  = e >> 6;             // 0..143
            int k    = rem % 9;
            int ci   = rem / 9;
            w_t[(ci * 9 + k) * 64 + cout] =
                wgt[((size_t)cout * CIN + cb * 16 + ci) * 9 + k];
        }
        __syncthreads();

        for (int ci = 0; ci < 16; ++ci) {
#pragma unroll
            for (int kh = 0; kh < 3; ++kh) {
#pragma unroll
                for (int kw = 0; kw < 3; ++kw) {
                    const float4 wv = *(const float4*)&w_t[(ci * 9 + kh * 3 + kw) * 64 + c4];
#pragma unroll
                    for (int i = 0; i < 7; ++i) {
                        float a = in_t[ci * 570 + kh * 114 + kw + rowoff[i]];
                        acc[i][0] = fmaf(a, wv.x, acc[i][0]);
                        acc[i][1] = fmaf(a, wv.y, acc[i][1]);
                        acc[i][2] = fmaf(a, wv.z, acc[i][2]);
                        acc[i][3] = fmaf(a, wv.w, acc[i][3]);
                    }
                }
            }
        }
    }

    // BN(eval) + ReLU params for this thread's 4 couts
    float sc[4], bb[4];
#pragma unroll
    for (int j = 0; j < 4; ++j) {
        float s = gamma[c4 + j] * rsqrtf(var[c4 + j] + 1e-5f);
        sc[j] = s;
        bb[j] = beta[c4 + j] - mean[c4 + j] * s;
    }

    const int b = bt >> 3, t = bt & 7;
    float* fdst = ynp + ((size_t)b * TPD + (t + 2)) * (size_t)(HPD * WPD * CH);

#pragma unroll
    for (int i = 0; i < 7; ++i) {
        float4 yv;
        yv.x = fmaxf(fmaf(acc[i][0], sc[0], bb[0]), 0.f);
        yv.y = fmaxf(fmaf(acc[i][1], sc[1], bb[1]), 0.f);
        yv.z = fmaxf(fmaf(acc[i][2], sc[2], bb[2]), 0.f);
        yv.w = fmaxf(fmaf(acc[i][3], sc[3], bb[3]), 0.f);
        float ss = yv.x*yv.x + yv.y*yv.y + yv.z*yv.z + yv.w*yv.w;
        // reduce across the 16 cout-lanes sharing this pixel (consecutive lanes)
        ss += __shfl_xor(ss, 1);
        ss += __shfl_xor(ss, 2);
        ss += __shfl_xor(ss, 4);
        ss += __shfl_xor(ss, 8);
        float inv = rsqrtf(ss + 1e-6f);
        yv.x *= inv; yv.y *= inv; yv.z *= inv; yv.w *= inv;
        *(float4*)&fdst[((size_t)(h0 + prow[i] + 4) * WPD + (pcol[i] + 4)) * CH + c4] = yv;
    }
}

// ---------------------------------------------------------------------------
// Kernel 2: windowed correlation.
// out[b,t,h,w,0,l,u,v] = sum_c yn[b,t,c,h,w] * ynp[b, t+l, c, h+u, w+v] (padded coords)
// Block: 128 threads, 112 active as (r in 0..1, w in 0..55); one (b,t,row-pair).
// Channels chunked by 16; neighbor rows staged transposed in LDS [c][rr][col].
// ---------------------------------------------------------------------------
__global__ __launch_bounds__(128) void corr_k(
    const float* __restrict__ ynp, float* __restrict__ out)
{
    __shared__ float nbT[16 * NBSTR];      // 41,216 B

    const int tid  = threadIdx.x;
    const int h0   = blockIdx.x * 2;
    const int t    = blockIdx.y;
    const int b    = blockIdx.z;
    const int r    = tid / 56;
    const int wcol = tid - r * 56;
    const bool act = (tid < 112);

    const float* fb   = ynp + (size_t)b * ((size_t)TPD * HPD * WPD * CH);
    const float* cenp = fb + (((size_t)(t + 2) * HPD + (h0 + r + 4)) * WPD + (wcol + 4)) * CH;
    float* outp = out + ((((size_t)(b * TSEG + t) * HO + (h0 + r)) * WO + wcol) * 405);

    for (int l = 0; l < 5; ++l) {
        const float* nf = fb + ((size_t)(t + l) * HPD + h0) * (size_t)(WPD * CH);
        float acc[81];
#pragma unroll
        for (int i = 0; i < 81; ++i) acc[i] = 0.f;

        for (int cb = 0; cb < 4; ++cb) {
            __syncthreads();
            // stage 10 rows x 64 cols x 16 channels, transposed to [ci][rr][col]
            for (int e4 = tid; e4 < 2560; e4 += 128) {
                const int ci4 = e4 & 3;
                const int col = (e4 >> 2) & 63;
                const int rr  = e4 >> 8;                // 0..9
                const float4 v = *(const float4*)&nf[((size_t)rr * WPD + col) * CH + cb * 16 + ci4 * 4];
                const int ba = (ci4 * 4) * NBSTR + rr * 64 + col;
                nbT[ba]             = v.x;
                nbT[ba + NBSTR]     = v.y;
                nbT[ba + 2 * NBSTR] = v.z;
                nbT[ba + 3 * NBSTR] = v.w;
            }
            __syncthreads();

            if (act) {
                float c16[16];
#pragma unroll
                for (int j = 0; j < 4; ++j) {
                    const float4 cv = *(const float4*)&cenp[cb * 16 + j * 4];
                    c16[j * 4 + 0] = cv.x; c16[j * 4 + 1] = cv.y;
                    c16[j * 4 + 2] = cv.z; c16[j * 4 + 3] = cv.w;
                }
                const float* tb = &nbT[r * 64 + wcol];
#pragma unroll
                for (int u = 0; u < 9; ++u) {
#pragma unroll
                    for (int ci = 0; ci < 16; ++ci) {
                        const float a = c16[ci];
                        const float* bp = tb + ci * NBSTR + u * 64;
#pragma unroll
                        for (int v = 0; v < 9; ++v)
                            acc[u * 9 + v] = fmaf(a, bp[v], acc[u * 9 + v]);
                    }
                }
            }
        }

        if (act) {
            float* op = outp + l * 81;
#pragma unroll
            for (int i = 0; i < 81; ++i) op[i] = acc[i];
        }
    }
}

// ---------------------------------------------------------------------------
extern "C" void kernel_launch(void* const* d_in, const int* in_sizes, int n_in,
                              void* d_out, int out_size, void* d_ws, size_t ws_size,
                              hipStream_t stream)
{
    const float* x     = (const float*)d_in[0];
    const float* wgt   = (const float*)d_in[1];
    const float* gamma = (const float*)d_in[2];
    const float* beta  = (const float*)d_in[3];
    const float* mean  = (const float*)d_in[4];
    const float* var   = (const float*)d_in[5];
    float* out = (float*)d_out;
    float* ynp = (float*)d_ws;

    const size_t ynp_bytes = YNP_ELEMS * sizeof(float);
    if (ws_size < ynp_bytes) return;   // workspace too small: fail loudly via mismatch

    // zero the padded yn buffer (pads must be 0 every call; interior overwritten)
    hipMemsetAsync(d_ws, 0, ynp_bytes, stream);

    conv_norm_k<<<dim3(28, NBT), 256, 0, stream>>>(x, wgt, gamma, beta, mean, var, ynp);
    corr_k<<<dim3(28, TSEG, NBC), 128, 0, stream>>>(ynp, out);
}

// Round 2
// 1191.255 us; speedup vs baseline: 1.7388x; 1.7388x over previous
//
#include <hip/hip_runtime.h>
#include <hip/hip_bf16.h>

// Problem constants
#define TSEG 8
#define NBC 4          // clips
#define NBT 32         // B*T
#define CIN 256
#define CH 64
#define HIN 112
#define WIN_ 112
#define HO 56
#define WO 56
#define HPD 64
#define WPD 64
#define NBSTR 644      // padded LDS plane stride (floats) for corr staging

#define FRSZ ((size_t)(HPD * WPD * CH))     // 262144 floats per padded frame
#define ZF_OFF 73728                        // float offset of shared zero frame (after 294912 B of w'')
#define FRAMES_OFF (ZF_OFF + 262144)        // float offset of the 32 real frames
#define WS_TOTAL_BYTES ((size_t)(FRAMES_OFF + 32 * 262144) * 4)   // 34,897,920 B

typedef __attribute__((ext_vector_type(8))) short bf16x8;
typedef __attribute__((ext_vector_type(4))) float f32x4;

// ---------------------------------------------------------------------------
// Weight prep: w[cout][ci][kh][kw] fp32 -> w''[tap][cout][ci] bf16 (RNE)
// ---------------------------------------------------------------------------
__global__ __launch_bounds__(256) void wprep_k(
    const float* __restrict__ w, unsigned short* __restrict__ wpp)
{
    int e = blockIdx.x * 256 + threadIdx.x;     // < 147456
    int cout = e / 2304;
    int rem  = e - cout * 2304;
    int ci   = rem / 9;
    int tap  = rem - ci * 9;
    union { float f; unsigned u; } cv; cv.f = w[e];
    unsigned u = cv.u + 0x7fffu + ((cv.u >> 16) & 1u);
    wpp[((size_t)tap * 64 + cout) * 256 + ci] = (unsigned short)(u >> 16);
}

// ---------------------------------------------------------------------------
// Conv3x3 s2 p1 + BN + ReLU + per-pixel L2 norm, via bf16 MFMA implicit GEMM.
// Block: 256 thr = 4 waves; tile = 2 output rows x 64 couts.
// Wave wv: row r = wv>>1, cout-half nh = wv&1. Per wave M=64 (4 m-tiles), N=32.
// K = 9 taps x 256 ci, chunked by 32 ci; input tile LDS-staged bf16 swizzled.
// ---------------------------------------------------------------------------
__global__ __launch_bounds__(256) void conv_mfma_k(
    const float* __restrict__ x, const unsigned short* __restrict__ wpp,
    const float* __restrict__ gamma, const float* __restrict__ beta,
    const float* __restrict__ mean, const float* __restrict__ var,
    float* __restrict__ frames)
{
    __shared__ unsigned short in_lds[5 * 120 * 32];   // 38,400 B, swizzled
    __shared__ float sq[2][2][64];

    const int tid  = threadIdx.x;
    const int lane = tid & 63;
    const int wv   = tid >> 6;
    const int r    = wv >> 1;        // wave's output row within block (0/1)
    const int nh   = wv & 1;         // cout half (0/1)
    const int l15  = lane & 15;
    const int l4   = lane >> 4;      // 0..3
    const int hb   = blockIdx.x;     // 0..27
    const int bt   = blockIdx.y;     // 0..31

    const float* xb = x + (size_t)bt * (CIN * HIN * WIN_);

    f32x4 acc[4][2];
#pragma unroll
    for (int mt = 0; mt < 4; ++mt) {
        acc[mt][0] = (f32x4){0.f, 0.f, 0.f, 0.f};
        acc[mt][1] = (f32x4){0.f, 0.f, 0.f, 0.f};
    }

    // A-read byte offsets within a row-plane (per m-tile, per kw), swizzled
    int a_off[4][3];
#pragma unroll
    for (int mt = 0; mt < 4; ++mt) {
        int c = mt * 16 + l15; if (c > 55) c = 55;   // clamp pad pixels
#pragma unroll
        for (int kw = 0; kw < 3; ++kw) {
            int col = 2 * c + kw;                    // LDS col (input col + 1)
            int ba  = col * 64 + l4 * 16;
            ba ^= ((col >> 1) & 7) << 4;
            a_off[mt][kw] = ba;
        }
    }

    // B fragment base pointers (w''[tap][cout][ci], lane holds 8 contiguous ci)
    const unsigned short* bptr0 = wpp + ((size_t)(nh * 32 + l15) * 256 + l4 * 8);
    const unsigned short* bptr1 = wpp + ((size_t)(nh * 32 + 16 + l15) * 256 + l4 * 8);

    const int ih0 = 4 * hb - 1;

    for (int cb = 0; cb < 8; ++cb) {
        __syncthreads();
        // ---- stage 5 rows x 113 cols x 32 ci as bf16 into swizzled LDS ----
#pragma unroll
        for (int j = 0; j < 5; ++j) {
            const int jj  = wv + j * 4;              // 0..19
            const int row = jj >> 2, cig = jj & 3;
            const int ih  = ih0 + row;
            const int ihc = ih < 0 ? 0 : (ih > 111 ? 111 : ih);
            const float* xr = xb + ((size_t)(cb * 32 + cig * 8) * HIN + ihc) * WIN_;
            const bool rowin = (ih >= 0) && (ih < HIN);
#pragma unroll
            for (int p = 0; p < 2; ++p) {
                const int col = lane + p * 64;       // LDS col
                if (col < 113) {
                    const int iw  = col - 1;
                    const int iwc = iw < 0 ? 0 : iw;
                    const bool inb = rowin && (iw >= 0);
                    unsigned pk[4];
#pragma unroll
                    for (int q = 0; q < 4; ++q) {
                        float v0 = xr[(size_t)(2 * q) * HIN * WIN_ + iwc];
                        float v1 = xr[(size_t)(2 * q + 1) * HIN * WIN_ + iwc];
                        v0 = inb ? v0 : 0.f;
                        v1 = inb ? v1 : 0.f;
                        union { float f; unsigned u; } c0, c1; c0.f = v0; c1.f = v1;
                        unsigned u0 = c0.u + 0x7fffu + ((c0.u >> 16) & 1u);
                        unsigned u1 = c1.u + 0x7fffu + ((c1.u >> 16) & 1u);
                        pk[q] = (u0 >> 16) | (u1 & 0xffff0000u);
                    }
                    int ba = (row * 120 + col) * 64 + cig * 16;
                    ba ^= ((col >> 1) & 7) << 4;
                    *(uint4*)((char*)in_lds + ba) = make_uint4(pk[0], pk[1], pk[2], pk[3]);
                }
            }
        }
        __syncthreads();

        // ---- 9 taps x (4 m-tiles x 2 n-tiles) MFMAs on this ci-chunk ----
        const int rowb = (2 * r) * 7680;             // row-plane byte stride 120*32*2
#pragma unroll
        for (int kh = 0; kh < 3; ++kh) {
            const int rb = rowb + kh * 7680;
#pragma unroll
            for (int kw = 0; kw < 3; ++kw) {
                const int tap = kh * 3 + kw;
                const bf16x8 bf0 = *(const bf16x8*)(bptr0 + tap * 16384 + cb * 32);
                const bf16x8 bf1 = *(const bf16x8*)(bptr1 + tap * 16384 + cb * 32);
#pragma unroll
                for (int mt = 0; mt < 4; ++mt) {
                    const bf16x8 af = *(const bf16x8*)((const char*)in_lds + (rb + a_off[mt][kw]));
                    acc[mt][0] = __builtin_amdgcn_mfma_f32_16x16x32_bf16(af, bf0, acc[mt][0], 0, 0, 0);
                    acc[mt][1] = __builtin_amdgcn_mfma_f32_16x16x32_bf16(af, bf1, acc[mt][1], 0, 0, 0);
                }
            }
        }
    }

    // ---- epilogue: BN + ReLU + cross-lane/wave L2 norm + store fp32 ----
    const int cout0 = nh * 32 + l15;
    const int cout1 = cout0 + 16;
    const float sc0 = gamma[cout0] * rsqrtf(var[cout0] + 1e-5f);
    const float bb0 = beta[cout0] - mean[cout0] * sc0;
    const float sc1 = gamma[cout1] * rsqrtf(var[cout1] + 1e-5f);
    const float bb1 = beta[cout1] - mean[cout1] * sc1;

    float yv[4][2][4];
    float ssr[4][4];
#pragma unroll
    for (int mt = 0; mt < 4; ++mt) {
#pragma unroll
        for (int reg = 0; reg < 4; ++reg) {
            float y0 = fmaxf(fmaf(acc[mt][0][reg], sc0, bb0), 0.f);
            float y1 = fmaxf(fmaf(acc[mt][1][reg], sc1, bb1), 0.f);
            yv[mt][0][reg] = y0; yv[mt][1][reg] = y1;
            float ss = y0 * y0 + y1 * y1;
            ss += __shfl_xor(ss, 1);
            ss += __shfl_xor(ss, 2);
            ss += __shfl_xor(ss, 4);
            ss += __shfl_xor(ss, 8);
            ssr[mt][reg] = ss;         // this wave's 32-cout partial for pixel
        }
    }
    if (l15 == 0) {
#pragma unroll
        for (int mt = 0; mt < 4; ++mt)
#pragma unroll
            for (int reg = 0; reg < 4; ++reg)
                sq[r][nh][mt * 16 + l4 * 4 + reg] = ssr[mt][reg];
    }
    __syncthreads();

    const int h = 2 * hb + r;
    float* fdst = frames + (size_t)bt * FRSZ + (size_t)(h + 4) * WPD * CH;
#pragma unroll
    for (int mt = 0; mt < 4; ++mt) {
#pragma unroll
        for (int reg = 0; reg < 4; ++reg) {
            const int c = mt * 16 + l4 * 4 + reg;
            if (c < 56) {
                const float tot = sq[r][0][c] + sq[r][1][c];
                const float inv = rsqrtf(tot + 1e-6f);
                float* dp = fdst + (size_t)(c + 4) * CH;
                dp[cout0] = yv[mt][0][reg] * inv;
                dp[cout1] = yv[mt][1][reg] * inv;
            }
        }
    }
}

// ---------------------------------------------------------------------------
// Kernel 2: windowed correlation (unchanged logic; frame indirection to the
// shared zero frame replaces the materialized temporal padding).
// ---------------------------------------------------------------------------
__global__ __launch_bounds__(128) void corr_k(
    const float* __restrict__ frames, const float* __restrict__ zf,
    float* __restrict__ out)
{
    __shared__ float nbT[16 * NBSTR];      // 41,216 B

    const int tid  = threadIdx.x;
    const int h0   = blockIdx.x * 2;
    const int t    = blockIdx.y;
    const int b    = blockIdx.z;
    const int r    = tid / 56;
    const int wcol = tid - r * 56;
    const bool act = (tid < 112);

    const float* cenp = frames + (size_t)(b * TSEG + t) * FRSZ
                      + (((size_t)(h0 + r + 4) * WPD) + (wcol + 4)) * CH;
    float* outp = out + ((((size_t)(b * TSEG + t) * HO + (h0 + r)) * WO + wcol) * 405);

    for (int l = 0; l < 5; ++l) {
        const int f = t + l;               // padded frame index 0..11
        const float* frp = (f < 2 || f > 9) ? zf
                          : (frames + (size_t)(b * TSEG + f - 2) * FRSZ);
        const float* nf = frp + (size_t)h0 * (WPD * CH);
        float acc[81];
#pragma unroll
        for (int i = 0; i < 81; ++i) acc[i] = 0.f;

        for (int cb = 0; cb < 4; ++cb) {
            __syncthreads();
            // stage 10 rows x 64 cols x 16 channels, transposed to [ci][rr][col]
            for (int e4 = tid; e4 < 2560; e4 += 128) {
                const int ci4 = e4 & 3;
                const int col = (e4 >> 2) & 63;
                const int rr  = e4 >> 8;                // 0..9
                const float4 v = *(const float4*)&nf[((size_t)rr * WPD + col) * CH + cb * 16 + ci4 * 4];
                const int ba = (ci4 * 4) * NBSTR + rr * 64 + col;
                nbT[ba]             = v.x;
                nbT[ba + NBSTR]     = v.y;
                nbT[ba + 2 * NBSTR] = v.z;
                nbT[ba + 3 * NBSTR] = v.w;
            }
            __syncthreads();

            if (act) {
                float c16[16];
#pragma unroll
                for (int j = 0; j < 4; ++j) {
                    const float4 cv = *(const float4*)&cenp[cb * 16 + j * 4];
                    c16[j * 4 + 0] = cv.x; c16[j * 4 + 1] = cv.y;
                    c16[j * 4 + 2] = cv.z; c16[j * 4 + 3] = cv.w;
                }
                const float* tb = &nbT[r * 64 + wcol];
#pragma unroll
                for (int u = 0; u < 9; ++u) {
#pragma unroll
                    for (int ci = 0; ci < 16; ++ci) {
                        const float a = c16[ci];
                        const float* bp = tb + ci * NBSTR + u * 64;
#pragma unroll
                        for (int v = 0; v < 9; ++v)
                            acc[u * 9 + v] = fmaf(a, bp[v], acc[u * 9 + v]);
                    }
                }
            }
        }

        if (act) {
            float* op = outp + l * 81;
#pragma unroll
            for (int i = 0; i < 81; ++i) op[i] = acc[i];
        }
    }
}

// ---------------------------------------------------------------------------
extern "C" void kernel_launch(void* const* d_in, const int* in_sizes, int n_in,
                              void* d_out, int out_size, void* d_ws, size_t ws_size,
                              hipStream_t stream)
{
    const float* x     = (const float*)d_in[0];
    const float* wgt   = (const float*)d_in[1];
    const float* gamma = (const float*)d_in[2];
    const float* beta  = (const float*)d_in[3];
    const float* mean  = (const float*)d_in[4];
    const float* var   = (const float*)d_in[5];
    float* out = (float*)d_out;

    unsigned short* wpp = (unsigned short*)d_ws;
    float* wsf    = (float*)d_ws;
    float* zf     = wsf + ZF_OFF;
    float* frames = wsf + FRAMES_OFF;

    if (ws_size < WS_TOTAL_BYTES) return;

    hipMemsetAsync(d_ws, 0, WS_TOTAL_BYTES, stream);
    wprep_k<<<dim3(576), 256, 0, stream>>>(wgt, wpp);
    conv_mfma_k<<<dim3(28, NBT), 256, 0, stream>>>(x, wpp, gamma, beta, mean, var, frames);
    corr_k<<<dim3(28, TSEG, NBC), 128, 0, stream>>>(frames, zf, out);
}

// Round 3
// 337.390 us; speedup vs baseline: 6.1394x; 3.5308x over previous
//
#include <hip/hip_runtime.h>
#include <hip/hip_bf16.h>

// Problem constants
#define TSEG 8
#define NBC 4          // clips
#define NBT 32         // B*T
#define CIN 256
#define CH 64
#define HIN 112
#define WIN_ 112
#define HO 56
#define WO 56
#define HPD 64
#define WPD 64

#define FRSZE ((size_t)(HPD * WPD * CH))    // 262144 bf16 elems per padded frame
#define ZF_U   147456                        // ushort offset of zero frame (after 294912 B of w'')
#define FR_U   (ZF_U + 262144)               // ushort offset of the 32 real frames
#define WS_TOTAL_BYTES ((size_t)(FR_U + 32 * 262144) * 2)   // 17,596,416 B

typedef __attribute__((ext_vector_type(8))) short bf16x8;
typedef __attribute__((ext_vector_type(4))) float f32x4;

__device__ __forceinline__ unsigned short f2bf(float f) {
    union { float f; unsigned u; } c; c.f = f;
    unsigned u = c.u + 0x7fffu + ((c.u >> 16) & 1u);
    return (unsigned short)(u >> 16);
}

// ---------------------------------------------------------------------------
// Weight prep: w[cout][ci][kh][kw] fp32 -> w''[tap][cout][ci] bf16 (RNE)
// ---------------------------------------------------------------------------
__global__ __launch_bounds__(256) void wprep_k(
    const float* __restrict__ w, unsigned short* __restrict__ wpp)
{
    int e = blockIdx.x * 256 + threadIdx.x;     // < 147456
    int cout = e / 2304;
    int rem  = e - cout * 2304;
    int ci   = rem / 9;
    int tap  = rem - ci * 9;
    wpp[((size_t)tap * 64 + cout) * 256 + ci] = f2bf(w[e]);
}

// ---------------------------------------------------------------------------
// Conv3x3 s2 p1 + BN + ReLU + per-pixel L2 norm, via bf16 MFMA implicit GEMM.
// Writes bf16 padded frames [bt][h+4][w+4][c].
// ---------------------------------------------------------------------------
__global__ __launch_bounds__(256) void conv_mfma_k(
    const float* __restrict__ x, const unsigned short* __restrict__ wpp,
    const float* __restrict__ gamma, const float* __restrict__ beta,
    const float* __restrict__ mean, const float* __restrict__ var,
    unsigned short* __restrict__ frames)
{
    __shared__ unsigned short in_lds[5 * 120 * 32];   // 38,400 B, swizzled
    __shared__ float sq[2][2][64];

    const int tid  = threadIdx.x;
    const int lane = tid & 63;
    const int wv   = tid >> 6;
    const int r    = wv >> 1;        // wave's output row within block (0/1)
    const int nh   = wv & 1;         // cout half (0/1)
    const int l15  = lane & 15;
    const int l4   = lane >> 4;      // 0..3
    const int hb   = blockIdx.x;     // 0..27
    const int bt   = blockIdx.y;     // 0..31

    const float* xb = x + (size_t)bt * (CIN * HIN * WIN_);

    f32x4 acc[4][2];
#pragma unroll
    for (int mt = 0; mt < 4; ++mt) {
        acc[mt][0] = (f32x4){0.f, 0.f, 0.f, 0.f};
        acc[mt][1] = (f32x4){0.f, 0.f, 0.f, 0.f};
    }

    // A-read byte offsets within a row-plane (per m-tile, per kw), swizzled
    int a_off[4][3];
#pragma unroll
    for (int mt = 0; mt < 4; ++mt) {
        int c = mt * 16 + l15; if (c > 55) c = 55;   // clamp pad pixels
#pragma unroll
        for (int kw = 0; kw < 3; ++kw) {
            int col = 2 * c + kw;                    // LDS col (input col + 1)
            int ba  = col * 64 + l4 * 16;
            ba ^= ((col >> 1) & 7) << 4;
            a_off[mt][kw] = ba;
        }
    }

    // B fragment base pointers (w''[tap][cout][ci], lane holds 8 contiguous ci)
    const unsigned short* bptr0 = wpp + ((size_t)(nh * 32 + l15) * 256 + l4 * 8);
    const unsigned short* bptr1 = wpp + ((size_t)(nh * 32 + 16 + l15) * 256 + l4 * 8);

    const int ih0 = 4 * hb - 1;

    for (int cb = 0; cb < 8; ++cb) {
        __syncthreads();
        // ---- stage 5 rows x 113 cols x 32 ci as bf16 into swizzled LDS ----
#pragma unroll
        for (int j = 0; j < 5; ++j) {
            const int jj  = wv + j * 4;              // 0..19
            const int row = jj >> 2, cig = jj & 3;
            const int ih  = ih0 + row;
            const int ihc = ih < 0 ? 0 : (ih > 111 ? 111 : ih);
            const float* xr = xb + ((size_t)(cb * 32 + cig * 8) * HIN + ihc) * WIN_;
            const bool rowin = (ih >= 0) && (ih < HIN);
#pragma unroll
            for (int p = 0; p < 2; ++p) {
                const int col = lane + p * 64;       // LDS col
                if (col < 113) {
                    const int iw  = col - 1;
                    const int iwc = iw < 0 ? 0 : iw;
                    const bool inb = rowin && (iw >= 0);
                    unsigned pk[4];
#pragma unroll
                    for (int q = 0; q < 4; ++q) {
                        float v0 = xr[(size_t)(2 * q) * HIN * WIN_ + iwc];
                        float v1 = xr[(size_t)(2 * q + 1) * HIN * WIN_ + iwc];
                        v0 = inb ? v0 : 0.f;
                        v1 = inb ? v1 : 0.f;
                        union { float f; unsigned u; } c0, c1; c0.f = v0; c1.f = v1;
                        unsigned u0 = c0.u + 0x7fffu + ((c0.u >> 16) & 1u);
                        unsigned u1 = c1.u + 0x7fffu + ((c1.u >> 16) & 1u);
                        pk[q] = (u0 >> 16) | (u1 & 0xffff0000u);
                    }
                    int ba = (row * 120 + col) * 64 + cig * 16;
                    ba ^= ((col >> 1) & 7) << 4;
                    *(uint4*)((char*)in_lds + ba) = make_uint4(pk[0], pk[1], pk[2], pk[3]);
                }
            }
        }
        __syncthreads();

        // ---- 9 taps x (4 m-tiles x 2 n-tiles) MFMAs on this ci-chunk ----
        const int rowb = (2 * r) * 7680;             // row-plane byte stride 120*32*2
#pragma unroll
        for (int kh = 0; kh < 3; ++kh) {
            const int rb = rowb + kh * 7680;
#pragma unroll
            for (int kw = 0; kw < 3; ++kw) {
                const int tap = kh * 3 + kw;
                const bf16x8 bf0 = *(const bf16x8*)(bptr0 + tap * 16384 + cb * 32);
                const bf16x8 bf1 = *(const bf16x8*)(bptr1 + tap * 16384 + cb * 32);
#pragma unroll
                for (int mt = 0; mt < 4; ++mt) {
                    const bf16x8 af = *(const bf16x8*)((const char*)in_lds + (rb + a_off[mt][kw]));
                    acc[mt][0] = __builtin_amdgcn_mfma_f32_16x16x32_bf16(af, bf0, acc[mt][0], 0, 0, 0);
                    acc[mt][1] = __builtin_amdgcn_mfma_f32_16x16x32_bf16(af, bf1, acc[mt][1], 0, 0, 0);
                }
            }
        }
    }

    // ---- epilogue: BN + ReLU + cross-lane/wave L2 norm + store bf16 ----
    const int cout0 = nh * 32 + l15;
    const int cout1 = cout0 + 16;
    const float sc0 = gamma[cout0] * rsqrtf(var[cout0] + 1e-5f);
    const float bb0 = beta[cout0] - mean[cout0] * sc0;
    const float sc1 = gamma[cout1] * rsqrtf(var[cout1] + 1e-5f);
    const float bb1 = beta[cout1] - mean[cout1] * sc1;

    float yv[4][2][4];
    float ssr[4][4];
#pragma unroll
    for (int mt = 0; mt < 4; ++mt) {
#pragma unroll
        for (int reg = 0; reg < 4; ++reg) {
            float y0 = fmaxf(fmaf(acc[mt][0][reg], sc0, bb0), 0.f);
            float y1 = fmaxf(fmaf(acc[mt][1][reg], sc1, bb1), 0.f);
            yv[mt][0][reg] = y0; yv[mt][1][reg] = y1;
            float ss = y0 * y0 + y1 * y1;
            ss += __shfl_xor(ss, 1);
            ss += __shfl_xor(ss, 2);
            ss += __shfl_xor(ss, 4);
            ss += __shfl_xor(ss, 8);
            ssr[mt][reg] = ss;         // this wave's 32-cout partial for pixel
        }
    }
    if (l15 == 0) {
#pragma unroll
        for (int mt = 0; mt < 4; ++mt)
#pragma unroll
            for (int reg = 0; reg < 4; ++reg)
                sq[r][nh][mt * 16 + l4 * 4 + reg] = ssr[mt][reg];
    }
    __syncthreads();

    const int h = 2 * hb + r;
    unsigned short* fdst = frames + (size_t)bt * FRSZE + (size_t)(h + 4) * WPD * CH;
#pragma unroll
    for (int mt = 0; mt < 4; ++mt) {
#pragma unroll
        for (int reg = 0; reg < 4; ++reg) {
            const int c = mt * 16 + l4 * 4 + reg;
            if (c < 56) {
                const float tot = sq[r][0][c] + sq[r][1][c];
                const float inv = rsqrtf(tot + 1e-6f);
                unsigned short* dp = fdst + (size_t)(c + 4) * CH;
                dp[cout0] = f2bf(yv[mt][0][reg] * inv);
                dp[cout1] = f2bf(yv[mt][1][reg] * inv);
            }
        }
    }
}

// ---------------------------------------------------------------------------
// Kernel 2: windowed correlation via banded Gram matrices on MFMA.
// Block = (h, t, b), 4 waves; wave handles (l,u) pairs lu = wv, wv+4, ...
// G = Y(56x64) . Z(64x64)^T per (l,u); band out[w,v] = G[w, w+v].
// A/B fragments load directly from bf16 global frames (L2/L3 resident).
// ---------------------------------------------------------------------------
__global__ __launch_bounds__(256) void corr_mfma_k(
    const unsigned short* __restrict__ frames,
    const unsigned short* __restrict__ zf,
    float* __restrict__ out)
{
    const int tid  = threadIdx.x;
    const int lane = tid & 63;
    const int wv   = tid >> 6;
    const int l15  = lane & 15;
    const int l4   = lane >> 4;
    const int h    = blockIdx.x;     // 0..55
    const int t    = blockIdx.y;
    const int b    = blockIdx.z;
    const int bt   = b * TSEG + t;

    // A fragments: Y[w][c] from padded row h+4 of center frame (w = 16m + l15)
    const unsigned short* yrow = frames + (size_t)bt * FRSZE + (size_t)(h + 4) * (WPD * CH);
    bf16x8 af[4][2];
#pragma unroll
    for (int m = 0; m < 4; ++m) {
        int w = (m << 4) + l15; if (w > 55) w = 55;  // clamp (rows >=56 masked at store)
        const unsigned short* ap = yrow + (size_t)(w + 4) * CH + (l4 << 3);
        af[m][0] = *(const bf16x8*)(ap);
        af[m][1] = *(const bf16x8*)(ap + 32);
    }

    float* obase = out + (size_t)(bt * HO + h) * WO * 405;

    const int PM[7] = {0, 0, 1, 1, 2, 2, 3};
    const int PN[7] = {0, 1, 1, 2, 2, 3, 3};

    for (int lu = wv; lu < 45; lu += 4) {
        const int l = lu / 9, u = lu - 9 * l;
        const int f = t + l;                  // padded frame index 0..11
        const unsigned short* fr = (f < 2 || f > 9)
            ? zf : frames + (size_t)(b * TSEG + f - 2) * FRSZE;
        const unsigned short* zrow = fr + (size_t)(h + u) * (WPD * CH);

        // B fragments: Z[zc][c], zc = 16n + l15
        bf16x8 bfr[4][2];
#pragma unroll
        for (int n = 0; n < 4; ++n) {
            const unsigned short* bp = zrow + (size_t)((n << 4) + l15) * CH + (l4 << 3);
            bfr[n][0] = *(const bf16x8*)(bp);
            bfr[n][1] = *(const bf16x8*)(bp + 32);
        }

        f32x4 acc[7];
#pragma unroll
        for (int i = 0; i < 7; ++i) acc[i] = (f32x4){0.f, 0.f, 0.f, 0.f};
#pragma unroll
        for (int i = 0; i < 7; ++i) {
            acc[i] = __builtin_amdgcn_mfma_f32_16x16x32_bf16(af[PM[i]][0], bfr[PN[i]][0], acc[i], 0, 0, 0);
            acc[i] = __builtin_amdgcn_mfma_f32_16x16x32_bf16(af[PM[i]][1], bfr[PN[i]][1], acc[i], 0, 0, 0);
        }

        // band extraction: out[w, l*81 + u*9 + v] = G[w, w+v]
        float* op = obase + l * 81 + u * 9;
#pragma unroll
        for (int i = 0; i < 7; ++i) {
            const int zc = (PN[i] << 4) + l15;
            const int w0 = (PM[i] << 4) + (l4 << 2);
#pragma unroll
            for (int r = 0; r < 4; ++r) {
                const int w = w0 + r;
                const int v = zc - w;
                if (w < 56 && (unsigned)v <= 8u)
                    op[w * 405 + v] = acc[i][r];
            }
        }
    }
}

// ---------------------------------------------------------------------------
extern "C" void kernel_launch(void* const* d_in, const int* in_sizes, int n_in,
                              void* d_out, int out_size, void* d_ws, size_t ws_size,
                              hipStream_t stream)
{
    const float* x     = (const float*)d_in[0];
    const float* wgt   = (const float*)d_in[1];
    const float* gamma = (const float*)d_in[2];
    const float* beta  = (const float*)d_in[3];
    const float* mean  = (const float*)d_in[4];
    const float* var   = (const float*)d_in[5];
    float* out = (float*)d_out;

    unsigned short* wpp    = (unsigned short*)d_ws;
    unsigned short* zf     = wpp + ZF_U;
    unsigned short* frames = wpp + FR_U;

    if (ws_size < WS_TOTAL_BYTES) return;

    // zero frames + zero-frame (pads must be 0 every call; interiors overwritten)
    hipMemsetAsync(d_ws, 0, WS_TOTAL_BYTES, stream);
    wprep_k<<<dim3(576), 256, 0, stream>>>(wgt, wpp);
    conv_mfma_k<<<dim3(28, NBT), 256, 0, stream>>>(x, wpp, gamma, beta, mean, var, frames);
    corr_mfma_k<<<dim3(56, TSEG, NBC), 256, 0, stream>>>(frames, zf, out);
}

// Round 4
// 305.443 us; speedup vs baseline: 6.7816x; 1.1046x over previous
//
#include <hip/hip_runtime.h>
#include <hip/hip_bf16.h>

// Problem constants
#define TSEG 8
#define NBC 4          // clips
#define NBT 32         // B*T
#define CIN 256
#define CH 64
#define HIN 112
#define WIN_ 112
#define HO 56
#define WO 56
#define HPD 64
#define WPD 64

#define FRSZE ((size_t)(HPD * WPD * CH))    // 262144 bf16 elems per padded frame
#define ZF_U   147456                        // ushort offset of (now unused) zero frame
#define FR_U   (ZF_U + 262144)               // ushort offset of the 32 real frames
#define WS_TOTAL_BYTES ((size_t)(FR_U + 32 * 262144) * 2)   // 17,596,416 B

typedef __attribute__((ext_vector_type(8))) short bf16x8;
typedef __attribute__((ext_vector_type(4))) float f32x4;

__device__ __forceinline__ unsigned short f2bf(float f) {
    union { float f; unsigned u; } c; c.f = f;
    unsigned u = c.u + 0x7fffu + ((c.u >> 16) & 1u);
    return (unsigned short)(u >> 16);
}

// ---------------------------------------------------------------------------
// Weight prep: w[cout][ci][kh][kw] fp32 -> w''[tap][cout][ci] bf16 (RNE)
// ---------------------------------------------------------------------------
__global__ __launch_bounds__(256) void wprep_k(
    const float* __restrict__ w, unsigned short* __restrict__ wpp)
{
    int e = blockIdx.x * 256 + threadIdx.x;     // < 147456
    int cout = e / 2304;
    int rem  = e - cout * 2304;
    int ci   = rem / 9;
    int tap  = rem - ci * 9;
    wpp[((size_t)tap * 64 + cout) * 256 + ci] = f2bf(w[e]);
}

// ---------------------------------------------------------------------------
// Conv3x3 s2 p1 + BN + ReLU + per-pixel L2 norm, via bf16 MFMA implicit GEMM.
// Writes bf16 padded frames [bt][h+4][w+4][c].   (unchanged from R3)
// ---------------------------------------------------------------------------
__global__ __launch_bounds__(256) void conv_mfma_k(
    const float* __restrict__ x, const unsigned short* __restrict__ wpp,
    const float* __restrict__ gamma, const float* __restrict__ beta,
    const float* __restrict__ mean, const float* __restrict__ var,
    unsigned short* __restrict__ frames)
{
    __shared__ unsigned short in_lds[5 * 120 * 32];   // 38,400 B, swizzled
    __shared__ float sq[2][2][64];

    const int tid  = threadIdx.x;
    const int lane = tid & 63;
    const int wv   = tid >> 6;
    const int r    = wv >> 1;        // wave's output row within block (0/1)
    const int nh   = wv & 1;         // cout half (0/1)
    const int l15  = lane & 15;
    const int l4   = lane >> 4;      // 0..3
    const int hb   = blockIdx.x;     // 0..27
    const int bt   = blockIdx.y;     // 0..31

    const float* xb = x + (size_t)bt * (CIN * HIN * WIN_);

    f32x4 acc[4][2];
#pragma unroll
    for (int mt = 0; mt < 4; ++mt) {
        acc[mt][0] = (f32x4){0.f, 0.f, 0.f, 0.f};
        acc[mt][1] = (f32x4){0.f, 0.f, 0.f, 0.f};
    }

    // A-read byte offsets within a row-plane (per m-tile, per kw), swizzled
    int a_off[4][3];
#pragma unroll
    for (int mt = 0; mt < 4; ++mt) {
        int c = mt * 16 + l15; if (c > 55) c = 55;   // clamp pad pixels
#pragma unroll
        for (int kw = 0; kw < 3; ++kw) {
            int col = 2 * c + kw;                    // LDS col (input col + 1)
            int ba  = col * 64 + l4 * 16;
            ba ^= ((col >> 1) & 7) << 4;
            a_off[mt][kw] = ba;
        }
    }

    // B fragment base pointers (w''[tap][cout][ci], lane holds 8 contiguous ci)
    const unsigned short* bptr0 = wpp + ((size_t)(nh * 32 + l15) * 256 + l4 * 8);
    const unsigned short* bptr1 = wpp + ((size_t)(nh * 32 + 16 + l15) * 256 + l4 * 8);

    const int ih0 = 4 * hb - 1;

    for (int cb = 0; cb < 8; ++cb) {
        __syncthreads();
        // ---- stage 5 rows x 113 cols x 32 ci as bf16 into swizzled LDS ----
#pragma unroll
        for (int j = 0; j < 5; ++j) {
            const int jj  = wv + j * 4;              // 0..19
            const int row = jj >> 2, cig = jj & 3;
            const int ih  = ih0 + row;
            const int ihc = ih < 0 ? 0 : (ih > 111 ? 111 : ih);
            const float* xr = xb + ((size_t)(cb * 32 + cig * 8) * HIN + ihc) * WIN_;
            const bool rowin = (ih >= 0) && (ih < HIN);
#pragma unroll
            for (int p = 0; p < 2; ++p) {
                const int col = lane + p * 64;       // LDS col
                if (col < 113) {
                    const int iw  = col - 1;
                    const int iwc = iw < 0 ? 0 : iw;
                    const bool inb = rowin && (iw >= 0);
                    unsigned pk[4];
#pragma unroll
                    for (int q = 0; q < 4; ++q) {
                        float v0 = xr[(size_t)(2 * q) * HIN * WIN_ + iwc];
                        float v1 = xr[(size_t)(2 * q + 1) * HIN * WIN_ + iwc];
                        v0 = inb ? v0 : 0.f;
                        v1 = inb ? v1 : 0.f;
                        union { float f; unsigned u; } c0, c1; c0.f = v0; c1.f = v1;
                        unsigned u0 = c0.u + 0x7fffu + ((c0.u >> 16) & 1u);
                        unsigned u1 = c1.u + 0x7fffu + ((c1.u >> 16) & 1u);
                        pk[q] = (u0 >> 16) | (u1 & 0xffff0000u);
                    }
                    int ba = (row * 120 + col) * 64 + cig * 16;
                    ba ^= ((col >> 1) & 7) << 4;
                    *(uint4*)((char*)in_lds + ba) = make_uint4(pk[0], pk[1], pk[2], pk[3]);
                }
            }
        }
        __syncthreads();

        // ---- 9 taps x (4 m-tiles x 2 n-tiles) MFMAs on this ci-chunk ----
        const int rowb = (2 * r) * 7680;             // row-plane byte stride 120*32*2
#pragma unroll
        for (int kh = 0; kh < 3; ++kh) {
            const int rb = rowb + kh * 7680;
#pragma unroll
            for (int kw = 0; kw < 3; ++kw) {
                const int tap = kh * 3 + kw;
                const bf16x8 bf0 = *(const bf16x8*)(bptr0 + tap * 16384 + cb * 32);
                const bf16x8 bf1 = *(const bf16x8*)(bptr1 + tap * 16384 + cb * 32);
#pragma unroll
                for (int mt = 0; mt < 4; ++mt) {
                    const bf16x8 af = *(const bf16x8*)((const char*)in_lds + (rb + a_off[mt][kw]));
                    acc[mt][0] = __builtin_amdgcn_mfma_f32_16x16x32_bf16(af, bf0, acc[mt][0], 0, 0, 0);
                    acc[mt][1] = __builtin_amdgcn_mfma_f32_16x16x32_bf16(af, bf1, acc[mt][1], 0, 0, 0);
                }
            }
        }
    }

    // ---- epilogue: BN + ReLU + cross-lane/wave L2 norm + store bf16 ----
    const int cout0 = nh * 32 + l15;
    const int cout1 = cout0 + 16;
    const float sc0 = gamma[cout0] * rsqrtf(var[cout0] + 1e-5f);
    const float bb0 = beta[cout0] - mean[cout0] * sc0;
    const float sc1 = gamma[cout1] * rsqrtf(var[cout1] + 1e-5f);
    const float bb1 = beta[cout1] - mean[cout1] * sc1;

    float yv[4][2][4];
    float ssr[4][4];
#pragma unroll
    for (int mt = 0; mt < 4; ++mt) {
#pragma unroll
        for (int reg = 0; reg < 4; ++reg) {
            float y0 = fmaxf(fmaf(acc[mt][0][reg], sc0, bb0), 0.f);
            float y1 = fmaxf(fmaf(acc[mt][1][reg], sc1, bb1), 0.f);
            yv[mt][0][reg] = y0; yv[mt][1][reg] = y1;
            float ss = y0 * y0 + y1 * y1;
            ss += __shfl_xor(ss, 1);
            ss += __shfl_xor(ss, 2);
            ss += __shfl_xor(ss, 4);
            ss += __shfl_xor(ss, 8);
            ssr[mt][reg] = ss;         // this wave's 32-cout partial for pixel
        }
    }
    if (l15 == 0) {
#pragma unroll
        for (int mt = 0; mt < 4; ++mt)
#pragma unroll
            for (int reg = 0; reg < 4; ++reg)
                sq[r][nh][mt * 16 + l4 * 4 + reg] = ssr[mt][reg];
    }
    __syncthreads();

    const int h = 2 * hb + r;
    unsigned short* fdst = frames + (size_t)bt * FRSZE + (size_t)(h + 4) * WPD * CH;
#pragma unroll
    for (int mt = 0; mt < 4; ++mt) {
#pragma unroll
        for (int reg = 0; reg < 4; ++reg) {
            const int c = mt * 16 + l4 * 4 + reg;
            if (c < 56) {
                const float tot = sq[r][0][c] + sq[r][1][c];
                const float inv = rsqrtf(tot + 1e-6f);
                unsigned short* dp = fdst + (size_t)(c + 4) * CH;
                dp[cout0] = f2bf(yv[mt][0][reg] * inv);
                dp[cout1] = f2bf(yv[mt][1][reg] * inv);
            }
        }
    }
}

// ---------------------------------------------------------------------------
// Kernel 2: windowed correlation via banded Gram matrices on MFMA.
// Block = (h, t, b), 4 waves. Per temporal offset l: waves split the 9 u's,
// band values go to an LDS slab [56][84]; then the block stores the dense
// 56x81 slab with coalesced dword runs. Pad frames -> zero-fill LDS directly.
// ---------------------------------------------------------------------------
__global__ __launch_bounds__(256) void corr_mfma_k(
    const unsigned short* __restrict__ frames, float* __restrict__ out)
{
    __shared__ float so[56 * 84];          // 18,816 B

    const int tid  = threadIdx.x;
    const int lane = tid & 63;
    const int wv   = tid >> 6;
    const int l15  = lane & 15;
    const int l4   = lane >> 4;
    const int h    = blockIdx.x;     // 0..55
    const int t    = blockIdx.y;
    const int b    = blockIdx.z;
    const int bt   = b * TSEG + t;

    // A fragments: Y[w][c] from padded row h+4 of center frame (w = 16m + l15)
    const unsigned short* yrow = frames + (size_t)bt * FRSZE + (size_t)(h + 4) * (WPD * CH);
    bf16x8 af[4][2];
#pragma unroll
    for (int m = 0; m < 4; ++m) {
        int w = (m << 4) + l15; if (w > 55) w = 55;  // clamp (rows >=56 masked)
        const unsigned short* ap = yrow + (size_t)(w + 4) * CH + (l4 << 3);
        af[m][0] = *(const bf16x8*)(ap);
        af[m][1] = *(const bf16x8*)(ap + 32);
    }

    float* obase = out + (size_t)(bt * HO + h) * (WO * 405);

    const int PM[7] = {0, 0, 1, 1, 2, 2, 3};
    const int PN[7] = {0, 1, 1, 2, 2, 3, 3};

    for (int l = 0; l < 5; ++l) {
        const int f = t + l;               // padded frame index 0..11
        const bool isPad = (f < 2) || (f > 9);

        if (isPad) {
            for (int e = tid; e < 56 * 84; e += 256) so[e] = 0.f;
        } else {
            const unsigned short* fr = frames + (size_t)(b * TSEG + f - 2) * FRSZE;
            for (int u = wv; u < 9; u += 4) {
                const unsigned short* zrow = fr + (size_t)(h + u) * (WPD * CH);
                // B fragments: Z[zc][c], zc = 16n + l15
                bf16x8 bfr[4][2];
#pragma unroll
                for (int n = 0; n < 4; ++n) {
                    const unsigned short* bp = zrow + (size_t)((n << 4) + l15) * CH + (l4 << 3);
                    bfr[n][0] = *(const bf16x8*)(bp);
                    bfr[n][1] = *(const bf16x8*)(bp + 32);
                }

                f32x4 acc[7];
#pragma unroll
                for (int i = 0; i < 7; ++i) acc[i] = (f32x4){0.f, 0.f, 0.f, 0.f};
#pragma unroll
                for (int i = 0; i < 7; ++i) {
                    acc[i] = __builtin_amdgcn_mfma_f32_16x16x32_bf16(af[PM[i]][0], bfr[PN[i]][0], acc[i], 0, 0, 0);
                    acc[i] = __builtin_amdgcn_mfma_f32_16x16x32_bf16(af[PM[i]][1], bfr[PN[i]][1], acc[i], 0, 0, 0);
                }

                // band extraction into LDS: so[w][u*9 + v] = G[w, w+v]
#pragma unroll
                for (int i = 0; i < 7; ++i) {
                    const int zc = (PN[i] << 4) + l15;
                    const int w0 = (PM[i] << 4) + (l4 << 2);
#pragma unroll
                    for (int rr = 0; rr < 4; ++rr) {
                        const int w = w0 + rr;
                        const int v = zc - w;
                        if (w < 56 && (unsigned)v <= 8u)
                            so[w * 84 + u * 9 + v] = acc[i][rr];
                    }
                }
            }
        }
        __syncthreads();

        // coalesced store of this l's dense 56x81 slab
        float* ob = obase + l * 81;
#pragma unroll
        for (int ww = 0; ww < 14; ++ww) {
            const int w = wv * 14 + ww;
            const float* sr = so + w * 84;
            float* orow = ob + (size_t)w * 405;
            orow[lane] = sr[lane];
            if (lane < 17) orow[lane + 64] = sr[lane + 64];
        }
        __syncthreads();
    }
}

// ---------------------------------------------------------------------------
extern "C" void kernel_launch(void* const* d_in, const int* in_sizes, int n_in,
                              void* d_out, int out_size, void* d_ws, size_t ws_size,
                              hipStream_t stream)
{
    const float* x     = (const float*)d_in[0];
    const float* wgt   = (const float*)d_in[1];
    const float* gamma = (const float*)d_in[2];
    const float* beta  = (const float*)d_in[3];
    const float* mean  = (const float*)d_in[4];
    const float* var   = (const float*)d_in[5];
    float* out = (float*)d_out;

    unsigned short* wpp    = (unsigned short*)d_ws;
    unsigned short* frames = wpp + FR_U;

    if (ws_size < WS_TOTAL_BYTES) return;

    // zero frames (pads must be 0 every call; interiors overwritten)
    hipMemsetAsync(d_ws, 0, WS_TOTAL_BYTES, stream);
    wprep_k<<<dim3(576), 256, 0, stream>>>(wgt, wpp);
    conv_mfma_k<<<dim3(28, NBT), 256, 0, stream>>>(x, wpp, gamma, beta, mean, var, frames);
    corr_mfma_k<<<dim3(56, TSEG, NBC), 256, 0, stream>>>(frames, out);
}

// Round 5
// 274.680 us; speedup vs baseline: 7.5411x; 1.1120x over previous
//
#include <hip/hip_runtime.h>
#include <hip/hip_bf16.h>

// Problem constants
#define TSEG 8
#define NBC 4          // clips
#define NBT 32         // B*T
#define CIN 256
#define CH 64
#define HIN 112
#define WIN_ 112
#define HO 56
#define WO 56
#define HPD 64
#define WPD 64

#define FRSZE ((size_t)(HPD * WPD * CH))    // 262144 bf16 elems per padded frame
#define ZF_U   147456                        // ushort offset of (unused) zero frame
#define FR_U   (ZF_U + 262144)               // ushort offset of the 32 real frames
#define WS_TOTAL_BYTES ((size_t)(FR_U + 32 * 262144) * 2)   // 17,596,416 B

typedef __attribute__((ext_vector_type(8))) short bf16x8;
typedef __attribute__((ext_vector_type(4))) float f32x4;

__device__ __forceinline__ unsigned short f2bf(float f) {
    union { float f; unsigned u; } c; c.f = f;
    unsigned u = c.u + 0x7fffu + ((c.u >> 16) & 1u);
    return (unsigned short)(u >> 16);
}

// ---------------------------------------------------------------------------
// Weight prep: w[cout][ci][kh][kw] fp32 -> w''[tap][cout][ci] bf16 (RNE)
// ---------------------------------------------------------------------------
__global__ __launch_bounds__(256) void wprep_k(
    const float* __restrict__ w, unsigned short* __restrict__ wpp)
{
    int e = blockIdx.x * 256 + threadIdx.x;     // < 147456
    int cout = e / 2304;
    int rem  = e - cout * 2304;
    int ci   = rem / 9;
    int tap  = rem - ci * 9;
    wpp[((size_t)tap * 64 + cout) * 256 + ci] = f2bf(w[e]);
}

// ---------------------------------------------------------------------------
// Conv3x3 s2 p1 + BN + ReLU + per-pixel L2 norm, via bf16 MFMA implicit GEMM.
// Writes bf16 padded frames [bt][h+4][w+4][c].   (unchanged from R3/R4)
// ---------------------------------------------------------------------------
__global__ __launch_bounds__(256) void conv_mfma_k(
    const float* __restrict__ x, const unsigned short* __restrict__ wpp,
    const float* __restrict__ gamma, const float* __restrict__ beta,
    const float* __restrict__ mean, const float* __restrict__ var,
    unsigned short* __restrict__ frames)
{
    __shared__ unsigned short in_lds[5 * 120 * 32];   // 38,400 B, swizzled
    __shared__ float sq[2][2][64];

    const int tid  = threadIdx.x;
    const int lane = tid & 63;
    const int wv   = tid >> 6;
    const int r    = wv >> 1;        // wave's output row within block (0/1)
    const int nh   = wv & 1;         // cout half (0/1)
    const int l15  = lane & 15;
    const int l4   = lane >> 4;      // 0..3
    const int hb   = blockIdx.x;     // 0..27
    const int bt   = blockIdx.y;     // 0..31

    const float* xb = x + (size_t)bt * (CIN * HIN * WIN_);

    f32x4 acc[4][2];
#pragma unroll
    for (int mt = 0; mt < 4; ++mt) {
        acc[mt][0] = (f32x4){0.f, 0.f, 0.f, 0.f};
        acc[mt][1] = (f32x4){0.f, 0.f, 0.f, 0.f};
    }

    // A-read byte offsets within a row-plane (per m-tile, per kw), swizzled
    int a_off[4][3];
#pragma unroll
    for (int mt = 0; mt < 4; ++mt) {
        int c = mt * 16 + l15; if (c > 55) c = 55;   // clamp pad pixels
#pragma unroll
        for (int kw = 0; kw < 3; ++kw) {
            int col = 2 * c + kw;                    // LDS col (input col + 1)
            int ba  = col * 64 + l4 * 16;
            ba ^= ((col >> 1) & 7) << 4;
            a_off[mt][kw] = ba;
        }
    }

    // B fragment base pointers (w''[tap][cout][ci], lane holds 8 contiguous ci)
    const unsigned short* bptr0 = wpp + ((size_t)(nh * 32 + l15) * 256 + l4 * 8);
    const unsigned short* bptr1 = wpp + ((size_t)(nh * 32 + 16 + l15) * 256 + l4 * 8);

    const int ih0 = 4 * hb - 1;

    for (int cb = 0; cb < 8; ++cb) {
        __syncthreads();
        // ---- stage 5 rows x 113 cols x 32 ci as bf16 into swizzled LDS ----
#pragma unroll
        for (int j = 0; j < 5; ++j) {
            const int jj  = wv + j * 4;              // 0..19
            const int row = jj >> 2, cig = jj & 3;
            const int ih  = ih0 + row;
            const int ihc = ih < 0 ? 0 : (ih > 111 ? 111 : ih);
            const float* xr = xb + ((size_t)(cb * 32 + cig * 8) * HIN + ihc) * WIN_;
            const bool rowin = (ih >= 0) && (ih < HIN);
#pragma unroll
            for (int p = 0; p < 2; ++p) {
                const int col = lane + p * 64;       // LDS col
                if (col < 113) {
                    const int iw  = col - 1;
                    const int iwc = iw < 0 ? 0 : iw;
                    const bool inb = rowin && (iw >= 0);
                    unsigned pk[4];
#pragma unroll
                    for (int q = 0; q < 4; ++q) {
                        float v0 = xr[(size_t)(2 * q) * HIN * WIN_ + iwc];
                        float v1 = xr[(size_t)(2 * q + 1) * HIN * WIN_ + iwc];
                        v0 = inb ? v0 : 0.f;
                        v1 = inb ? v1 : 0.f;
                        union { float f; unsigned u; } c0, c1; c0.f = v0; c1.f = v1;
                        unsigned u0 = c0.u + 0x7fffu + ((c0.u >> 16) & 1u);
                        unsigned u1 = c1.u + 0x7fffu + ((c1.u >> 16) & 1u);
                        pk[q] = (u0 >> 16) | (u1 & 0xffff0000u);
                    }
                    int ba = (row * 120 + col) * 64 + cig * 16;
                    ba ^= ((col >> 1) & 7) << 4;
                    *(uint4*)((char*)in_lds + ba) = make_uint4(pk[0], pk[1], pk[2], pk[3]);
                }
            }
        }
        __syncthreads();

        // ---- 9 taps x (4 m-tiles x 2 n-tiles) MFMAs on this ci-chunk ----
        const int rowb = (2 * r) * 7680;             // row-plane byte stride 120*32*2
#pragma unroll
        for (int kh = 0; kh < 3; ++kh) {
            const int rb = rowb + kh * 7680;
#pragma unroll
            for (int kw = 0; kw < 3; ++kw) {
                const int tap = kh * 3 + kw;
                const bf16x8 bf0 = *(const bf16x8*)(bptr0 + tap * 16384 + cb * 32);
                const bf16x8 bf1 = *(const bf16x8*)(bptr1 + tap * 16384 + cb * 32);
#pragma unroll
                for (int mt = 0; mt < 4; ++mt) {
                    const bf16x8 af = *(const bf16x8*)((const char*)in_lds + (rb + a_off[mt][kw]));
                    acc[mt][0] = __builtin_amdgcn_mfma_f32_16x16x32_bf16(af, bf0, acc[mt][0], 0, 0, 0);
                    acc[mt][1] = __builtin_amdgcn_mfma_f32_16x16x32_bf16(af, bf1, acc[mt][1], 0, 0, 0);
                }
            }
        }
    }

    // ---- epilogue: BN + ReLU + cross-lane/wave L2 norm + store bf16 ----
    const int cout0 = nh * 32 + l15;
    const int cout1 = cout0 + 16;
    const float sc0 = gamma[cout0] * rsqrtf(var[cout0] + 1e-5f);
    const float bb0 = beta[cout0] - mean[cout0] * sc0;
    const float sc1 = gamma[cout1] * rsqrtf(var[cout1] + 1e-5f);
    const float bb1 = beta[cout1] - mean[cout1] * sc1;

    float yv[4][2][4];
    float ssr[4][4];
#pragma unroll
    for (int mt = 0; mt < 4; ++mt) {
#pragma unroll
        for (int reg = 0; reg < 4; ++reg) {
            float y0 = fmaxf(fmaf(acc[mt][0][reg], sc0, bb0), 0.f);
            float y1 = fmaxf(fmaf(acc[mt][1][reg], sc1, bb1), 0.f);
            yv[mt][0][reg] = y0; yv[mt][1][reg] = y1;
            float ss = y0 * y0 + y1 * y1;
            ss += __shfl_xor(ss, 1);
            ss += __shfl_xor(ss, 2);
            ss += __shfl_xor(ss, 4);
            ss += __shfl_xor(ss, 8);
            ssr[mt][reg] = ss;         // this wave's 32-cout partial for pixel
        }
    }
    if (l15 == 0) {
#pragma unroll
        for (int mt = 0; mt < 4; ++mt)
#pragma unroll
            for (int reg = 0; reg < 4; ++reg)
                sq[r][nh][mt * 16 + l4 * 4 + reg] = ssr[mt][reg];
    }
    __syncthreads();

    const int h = 2 * hb + r;
    unsigned short* fdst = frames + (size_t)bt * FRSZE + (size_t)(h + 4) * WPD * CH;
#pragma unroll
    for (int mt = 0; mt < 4; ++mt) {
#pragma unroll
        for (int reg = 0; reg < 4; ++reg) {
            const int c = mt * 16 + l4 * 4 + reg;
            if (c < 56) {
                const float tot = sq[r][0][c] + sq[r][1][c];
                const float inv = rsqrtf(tot + 1e-6f);
                unsigned short* dp = fdst + (size_t)(c + 4) * CH;
                dp[cout0] = f2bf(yv[mt][0][reg] * inv);
                dp[cout1] = f2bf(yv[mt][1][reg] * inv);
            }
        }
    }
}

// ---------------------------------------------------------------------------
// Kernel 2: windowed correlation via banded Gram matrices on MFMA.
// One 64-thread block per (b, t, l, h): no barriers, perfect balance.
// 9-u loop fully unrolled with 3 rotating B-buffers (prefetch distance 2).
// Band extraction -> LDS slab [56][84], then coalesced global store.
// Pad (t,l) blocks store zeros directly.
// ---------------------------------------------------------------------------
__global__ __launch_bounds__(64) void corr_mfma_k(
    const unsigned short* __restrict__ frames, float* __restrict__ out)
{
    __shared__ float so[56 * 84];          // 18,816 B

    const int lane = threadIdx.x;
    const int l15  = lane & 15;
    const int l4   = lane >> 4;
    const int h    = blockIdx.x;           // 0..55
    const int tl   = blockIdx.y;           // 0..39
    const int t    = tl / 5;
    const int l    = tl - 5 * t;
    const int b    = blockIdx.z;
    const int bt   = b * TSEG + t;

    float* ob = out + (size_t)(bt * HO + h) * (WO * 405) + l * 81;

    const int f = t + l;                   // padded frame index 0..11
    if (f < 2 || f > 9) {
        // temporal pad: output is exactly zero
#pragma unroll
        for (int w = 0; w < 56; ++w) {
            float* orow = ob + (size_t)w * 405;
            orow[lane] = 0.f;
            if (lane < 17) orow[lane + 64] = 0.f;
        }
        return;
    }

    // A fragments: Y[w][c] from padded row h+4 of center frame (w = 16m + l15)
    const unsigned short* yrow = frames + (size_t)bt * FRSZE + (size_t)(h + 4) * (WPD * CH);
    bf16x8 af[4][2];
#pragma unroll
    for (int m = 0; m < 4; ++m) {
        int w = (m << 4) + l15; if (w > 55) w = 55;  // clamp (masked at extract)
        const unsigned short* ap = yrow + (size_t)(w + 4) * CH + (l4 << 3);
        af[m][0] = *(const bf16x8*)(ap);
        af[m][1] = *(const bf16x8*)(ap + 32);
    }

    const unsigned short* zb = frames + (size_t)(b * TSEG + f - 2) * FRSZE
                             + (size_t)h * (WPD * CH);

    const int PM[7] = {0, 0, 1, 1, 2, 2, 3};
    const int PN[7] = {0, 1, 1, 2, 2, 3, 3};

#define LOADB(buf, uu) { \
    const unsigned short* zr = zb + (size_t)(uu) * (WPD * CH); \
    _Pragma("unroll") \
    for (int n = 0; n < 4; ++n) { \
        const unsigned short* bp = zr + (size_t)((n << 4) + l15) * CH + (l4 << 3); \
        buf[n][0] = *(const bf16x8*)(bp); \
        buf[n][1] = *(const bf16x8*)(bp + 32); } }

#define COMPU(buf, uu) { \
    f32x4 acc[7]; \
    _Pragma("unroll") \
    for (int i = 0; i < 7; ++i) acc[i] = (f32x4){0.f, 0.f, 0.f, 0.f}; \
    _Pragma("unroll") \
    for (int i = 0; i < 7; ++i) { \
        acc[i] = __builtin_amdgcn_mfma_f32_16x16x32_bf16(af[PM[i]][0], buf[PN[i]][0], acc[i], 0, 0, 0); \
        acc[i] = __builtin_amdgcn_mfma_f32_16x16x32_bf16(af[PM[i]][1], buf[PN[i]][1], acc[i], 0, 0, 0); } \
    _Pragma("unroll") \
    for (int i = 0; i < 7; ++i) { \
        const int zc = (PN[i] << 4) + l15; \
        const int w0 = (PM[i] << 4) + (l4 << 2); \
        _Pragma("unroll") \
        for (int rr = 0; rr < 4; ++rr) { \
            const int w = w0 + rr; \
            const int v = zc - w; \
            if (w < 56 && (unsigned)v <= 8u) \
                so[w * 84 + (uu) * 9 + v] = acc[i][rr]; } } }

    bf16x8 b0[4][2], b1[4][2], b2[4][2];
    LOADB(b0, 0); LOADB(b1, 1);
    LOADB(b2, 2); COMPU(b0, 0);
    LOADB(b0, 3); COMPU(b1, 1);
    LOADB(b1, 4); COMPU(b2, 2);
    LOADB(b2, 5); COMPU(b0, 3);
    LOADB(b0, 6); COMPU(b1, 4);
    LOADB(b1, 7); COMPU(b2, 5);
    LOADB(b2, 8); COMPU(b0, 6);
    COMPU(b1, 7);
    COMPU(b2, 8);

#undef LOADB
#undef COMPU

    // coalesced store of the dense 56x81 slab (single wave, LDS->global)
#pragma unroll
    for (int w = 0; w < 56; ++w) {
        const float* sr = so + w * 84;
        float* orow = ob + (size_t)w * 405;
        orow[lane] = sr[lane];
        if (lane < 17) orow[lane + 64] = sr[lane + 64];
    }
}

// ---------------------------------------------------------------------------
extern "C" void kernel_launch(void* const* d_in, const int* in_sizes, int n_in,
                              void* d_out, int out_size, void* d_ws, size_t ws_size,
                              hipStream_t stream)
{
    const float* x     = (const float*)d_in[0];
    const float* wgt   = (const float*)d_in[1];
    const float* gamma = (const float*)d_in[2];
    const float* beta  = (const float*)d_in[3];
    const float* mean  = (const float*)d_in[4];
    const float* var   = (const float*)d_in[5];
    float* out = (float*)d_out;

    unsigned short* wpp    = (unsigned short*)d_ws;
    unsigned short* frames = wpp + FR_U;

    if (ws_size < WS_TOTAL_BYTES) return;

    // zero frames (pads must be 0 every call; interiors overwritten)
    hipMemsetAsync(d_ws, 0, WS_TOTAL_BYTES, stream);
    wprep_k<<<dim3(576), 256, 0, stream>>>(wgt, wpp);
    conv_mfma_k<<<dim3(28, NBT), 256, 0, stream>>>(x, wpp, gamma, beta, mean, var, frames);
    corr_mfma_k<<<dim3(56, 40, NBC), 64, 0, stream>>>(frames, out);
}